// Round 1
// baseline (274.016 us; speedup 1.0000x reference)
//
#include <hip/hip_runtime.h>

// Problem constants
static constexpr int   Bn  = 8;
static constexpr int   Cc  = 21;
static constexpr int   Hh  = 512;
static constexpr int   Ww  = 512;
static constexpr int   HWn = Hh * Ww;           // 262144 = 2^18
static constexpr int   Nn  = Bn * HWn;          // 2097152 pixels
static constexpr float MAXM = 0.5f;
static constexpr float Sc   = 30.0f;

// ws layout (all offsets in bytes):
//   0   : int    counts[21]
//   96  : double acc
//   128 : float  sm[21]    (= S * m_list[c])
static constexpr int WS_COUNTS = 0;
static constexpr int WS_ACC    = 96;
static constexpr int WS_SM     = 128;

// ---------------------------------------------------------------------------
// K1: class histogram. One int4 (4 labels) per thread, LDS-local atomics,
// then 21 global atomics per block.
__global__ __launch_bounds__(256) void hist_kernel(const int4* __restrict__ t4,
                                                   int* __restrict__ counts) {
    __shared__ int lh[Cc];
    int t = threadIdx.x;
    if (t < Cc) lh[t] = 0;
    __syncthreads();
    int tid = blockIdx.x * 256 + t;           // tid in [0, Nn/4)
    int4 v = t4[tid];
    atomicAdd(&lh[v.x], 1);
    atomicAdd(&lh[v.y], 1);
    atomicAdd(&lh[v.z], 1);
    atomicAdd(&lh[v.w], 1);
    __syncthreads();
    if (t < Cc) atomicAdd(&counts[t], lh[t]);
}

// ---------------------------------------------------------------------------
// K2: m_list = (counts + 1e-4)^(-1/4); m_list *= MAX_M / max(m_list);
// store sm[c] = S * m_list[c]. Single wave of 64.
__global__ __launch_bounds__(64) void mlist_kernel(const int* __restrict__ counts,
                                                   float* __restrict__ sm) {
    int t = threadIdx.x;
    float mval = 0.0f;
    if (t < Cc) {
        float cnt = (float)counts[t] + 1e-4f;
        mval = 1.0f / sqrtf(sqrtf(cnt));      // x^-0.25
    }
    float mx = mval;
    #pragma unroll
    for (int o = 32; o >= 1; o >>= 1) mx = fmaxf(mx, __shfl_down(mx, o));
    mx = __shfl(mx, 0);
    if (t < Cc) sm[t] = Sc * mval * (MAXM / mx);
}

// ---------------------------------------------------------------------------
// K3: main loss. One thread handles 4 consecutive pixels (float4 loads across
// the 21-class stride). Two-pass logsumexp over values held in registers.
__global__ __launch_bounds__(256) void loss_kernel(const float* __restrict__ pred,
                                                   const int4* __restrict__ t4,
                                                   const float* __restrict__ smg,
                                                   double* __restrict__ acc) {
    __shared__ float s_sm[Cc];
    int t = threadIdx.x;
    if (t < Cc) s_sm[t] = smg[t];
    __syncthreads();

    int tid = blockIdx.x * 256 + t;           // tid in [0, Nn/4)
    int n0  = tid * 4;
    int b   = n0 >> 18;                       // HWn = 2^18
    int hw  = n0 & (HWn - 1);
    const float4* p4 = (const float4*)(pred + (size_t)b * Cc * HWn + hw);

    int4 y4 = t4[tid];
    int ys[4] = {y4.x, y4.y, y4.z, y4.w};
    float smy[4];
    #pragma unroll
    for (int k = 0; k < 4; ++k) smy[k] = s_sm[ys[k]];

    float v[Cc][4];
    float mx[4] = {-1e30f, -1e30f, -1e30f, -1e30f};
    float vy[4] = {0.f, 0.f, 0.f, 0.f};

    #pragma unroll
    for (int c = 0; c < Cc; ++c) {
        float4 x = p4[(size_t)c * (HWn / 4)];
        float xs[4] = {x.x, x.y, x.z, x.w};
        #pragma unroll
        for (int k = 0; k < 4; ++k) {
            float val = Sc * xs[k] - (c == ys[k] ? smy[k] : 0.0f);
            v[c][k] = val;
            mx[k] = fmaxf(mx[k], val);
            if (c == ys[k]) vy[k] = val;      // cndmask select
        }
    }

    float nll = 0.0f;
    #pragma unroll
    for (int k = 0; k < 4; ++k) {
        float sum = 0.0f;
        #pragma unroll
        for (int c = 0; c < Cc; ++c) sum += __expf(v[c][k] - mx[k]);
        nll += __logf(sum) + mx[k] - vy[k];
    }

    // wave (64-lane) reduce
    #pragma unroll
    for (int o = 32; o >= 1; o >>= 1) nll += __shfl_down(nll, o);

    __shared__ float wsum[4];
    int wave = t >> 6;
    int lane = t & 63;
    if (lane == 0) wsum[wave] = nll;
    __syncthreads();
    if (t == 0) {
        float bsum = wsum[0] + wsum[1] + wsum[2] + wsum[3];
        atomicAdd(acc, (double)bsum);
    }
}

// ---------------------------------------------------------------------------
// K4: finalize mean.
__global__ void final_kernel(const double* __restrict__ acc, float* __restrict__ out) {
    out[0] = (float)(acc[0] / (double)Nn);
}

extern "C" void kernel_launch(void* const* d_in, const int* in_sizes, int n_in,
                              void* d_out, int out_size, void* d_ws, size_t ws_size,
                              hipStream_t stream) {
    const float* pred   = (const float*)d_in[0];
    const int*   target = (const int*)d_in[1];
    float*       out    = (float*)d_out;

    char* ws = (char*)d_ws;
    int*    counts = (int*)(ws + WS_COUNTS);
    double* acc    = (double*)(ws + WS_ACC);
    float*  sm     = (float*)(ws + WS_SM);

    // zero counts + acc (+ sm region for safety); ws is poisoned 0xAA each call
    hipMemsetAsync(d_ws, 0, 256, stream);

    const int nvec   = Nn / 4;                // 524288
    const int blocks = nvec / 256;            // 2048

    hist_kernel <<<blocks, 256, 0, stream>>>((const int4*)target, counts);
    mlist_kernel<<<1,       64, 0, stream>>>(counts, sm);
    loss_kernel <<<blocks, 256, 0, stream>>>(pred, (const int4*)target, sm, acc);
    final_kernel<<<1,        1, 0, stream>>>(acc, out);
}